// Round 12
// baseline (229.317 us; speedup 1.0000x reference)
//
#include <hip/hip_runtime.h>
#include <hip/hip_fp16.h>
#include <math.h>

#define IN_DIM 256
#define HID 32
#define NSEG 100000

typedef _Float16 half8 __attribute__((ext_vector_type(8)));
typedef __fp16  fp16x2 __attribute__((ext_vector_type(2)));   // cvt_pkrtz return type
typedef float floatx4 __attribute__((ext_vector_type(4)));

// Fused q/k projection (f16 MFMA, fp32 accum) + per-row dot + exp + segment-sum.
// R12: register-staged prefetch (no global_load_lds, no LDS round-trip for X),
// B fragments in LDS (32KB, conflict-free packed layout), 12 waves/CU.
// Loop: cvt raw(s)->a  [auto vmcnt(3)]  ->  issue raw(s+1) x16 + idx(s+1)
//       -> ds_read B + MFMA -> epilogue (seg preloaded last iter: vmcnt(19),
//       never drains the stage). Each wave keeps 16KB outstanding through its
//       entire compute phase; 12 waves/CU x 16KB >> latency-BW product.
__global__ __launch_bounds__(256, 3) void att_kernel(
    const float* __restrict__ x,
    const float* __restrict__ Wq, const float* __restrict__ bq,
    const float* __restrict__ Wk, const float* __restrict__ bk,
    const int* __restrict__ idx,
    float* __restrict__ e_out, float* __restrict__ segsum,
    int n, int nsub)
{
    __shared__ _Float16 BF[4 * 8 * 64 * 8];   // 32 KB packed B fragments

    const int tid = threadIdx.x;
    const int w  = tid >> 6, l = tid & 63;
    const int lr = l & 15,  lg = l >> 4;

    // ---- prologue: pack B fragments (r3-validated layout)
    // thread t owns W-row k=t; k = ks*32 + lg*8 + j ; col c'=cg*16+cr ; lane=lg*16+cr
    {
        const int ks = tid >> 5, lg2 = (tid >> 3) & 3, j = tid & 7;
        const float4* wqr = (const float4*)(Wq + (size_t)tid * HID);
        const float4* wkr = (const float4*)(Wk + (size_t)tid * HID);
#pragma unroll
        for (int i = 0; i < 8; ++i) {
            float4 vq = wqr[i];
            float4 vk = wkr[i];
            float fq[4] = { vq.x, vq.y, vq.z, vq.w };
            float fk[4] = { vk.x, vk.y, vk.z, vk.w };
#pragma unroll
            for (int u2 = 0; u2 < 4; ++u2) {
                int c = i * 4 + u2, cg = c >> 4, cr = c & 15;
                BF[(((cg    ) * 8 + ks) * 64 + lg2 * 16 + cr) * 8 + j] = (_Float16)fq[u2];
                BF[(((cg + 2) * 8 + ks) * 64 + lg2 * 16 + cr) * 8 + j] = (_Float16)fk[u2];
            }
        }
    }
    __syncthreads();   // BF read-only hereafter

    const float bq0 = bq[lr], bq1 = bq[lr + 16];
    const float bk0 = bk[lr], bk1 = bk[lr + 16];

    const _Float16* bfl = BF + (size_t)l * 8;  // chunk stride = 512 halfs

    const int gw      = blockIdx.x * 4 + w;
    const int gstride = gridDim.x * 4;

    int s = gw;
    if (s >= nsub) return;

    // lane's loads for subtile s: row = s*16 + lr, cols lg*8 + ks*32 .. +7
    float4 raw[16];
    {
        int row = s * 16 + lr; if (row >= n) row = n - 1;
        const float* xp = x + (size_t)row * IN_DIM + lg * 8;
#pragma unroll
        for (int ks = 0; ks < 8; ++ks) {
            raw[2 * ks]     = *(const float4*)(xp + ks * 32);
            raw[2 * ks + 1] = *(const float4*)(xp + ks * 32 + 4);
        }
    }
    int r_ep = s * 16 + lg * 4 + lr;
    int my_seg = idx[r_ep < n ? r_ep : (n - 1)];

    while (true) {
        const int snext = s + gstride;

        // ---- phase 1: convert raw(s) -> a (frees raw; waits only own loads)
        half8 a[8];
#pragma unroll
        for (int ks = 0; ks < 8; ++ks) {
            float4 v0 = raw[2 * ks], v1 = raw[2 * ks + 1];
            union { half8 h8; fp16x2 h2[4]; } u;
            u.h2[0] = __builtin_amdgcn_cvt_pkrtz(v0.x, v0.y);
            u.h2[1] = __builtin_amdgcn_cvt_pkrtz(v0.z, v0.w);
            u.h2[2] = __builtin_amdgcn_cvt_pkrtz(v1.x, v1.y);
            u.h2[3] = __builtin_amdgcn_cvt_pkrtz(v1.z, v1.w);
            a[ks] = u.h8;
        }
        __builtin_amdgcn_sched_barrier(0);

        // ---- phase 2: issue next stream (raw loads FIRST, then idx) —
        // clamped & unconditional so the FIFO count is deterministic
        int r_next, seg_next;
        {
            int sc = snext < nsub ? snext : s;        // clamp (last iter: reload s)
            int row = sc * 16 + lr; if (row >= n) row = n - 1;
            const float* xp = x + (size_t)row * IN_DIM + lg * 8;
#pragma unroll
            for (int ks = 0; ks < 8; ++ks) {
                raw[2 * ks]     = *(const float4*)(xp + ks * 32);
                raw[2 * ks + 1] = *(const float4*)(xp + ks * 32 + 4);
            }
            r_next = sc * 16 + lg * 4 + lr;
            seg_next = idx[r_next < n ? r_next : (n - 1)];
        }
        __builtin_amdgcn_sched_barrier(0);

        // ---- phase 3: B from LDS + MFMA (stage loads fly through this)
        floatx4 acc0 = {0.f,0.f,0.f,0.f}, acc1 = {0.f,0.f,0.f,0.f};
        floatx4 acc2 = {0.f,0.f,0.f,0.f}, acc3 = {0.f,0.f,0.f,0.f};
#pragma unroll
        for (int ks = 0; ks < 8; ++ks) {
            half8 b0 = *(const half8*)(bfl + (0 * 8 + ks) * 512);
            half8 b1 = *(const half8*)(bfl + (1 * 8 + ks) * 512);
            half8 b2 = *(const half8*)(bfl + (2 * 8 + ks) * 512);
            half8 b3 = *(const half8*)(bfl + (3 * 8 + ks) * 512);
            acc0 = __builtin_amdgcn_mfma_f32_16x16x32_f16(a[ks], b0, acc0, 0, 0, 0);
            acc1 = __builtin_amdgcn_mfma_f32_16x16x32_f16(a[ks], b1, acc1, 0, 0, 0);
            acc2 = __builtin_amdgcn_mfma_f32_16x16x32_f16(a[ks], b2, acc2, 0, 0, 0);
            acc3 = __builtin_amdgcn_mfma_f32_16x16x32_f16(a[ks], b3, acc3, 0, 0, 0);
        }

        // att = sum_h (qv+bq)*(kv+bk); reduce over the 16 col-lanes
        float p[4];
#pragma unroll
        for (int i2 = 0; i2 < 4; ++i2) {
            p[i2] = (acc0[i2] + bq0) * (acc2[i2] + bk0)
                  + (acc1[i2] + bq1) * (acc3[i2] + bk1);
            p[i2] += __shfl_xor(p[i2], 1);
            p[i2] += __shfl_xor(p[i2], 2);
            p[i2] += __shfl_xor(p[i2], 4);
            p[i2] += __shfl_xor(p[i2], 8);
        }

        // ---- epilogue: seg preloaded (consume = vmcnt(19), stage keeps flying);
        // store + atomic fire-and-forget
        if (lr < 4 && r_ep < n) {
            float pv = (lr & 1) ? ((lr & 2) ? p[3] : p[1])
                                : ((lr & 2) ? p[2] : p[0]);
            float e = __expf(pv);   // no max-subtract: |att| small enough for f32
            e_out[r_ep] = e;
            atomicAdd(&segsum[my_seg], e);
        }

        if (snext >= nsub) break;
        s = snext;
        r_ep = r_next;
        my_seg = seg_next;
    }
}

// out = e / segsum[idx], float4-vectorized
__global__ __launch_bounds__(256) void norm_kernel(
    const int* __restrict__ idx, const float* __restrict__ segsum,
    float* __restrict__ out, int n)
{
    int i = blockIdx.x * blockDim.x + threadIdx.x;
    int stride = gridDim.x * blockDim.x;
    int n4 = n >> 2;
    for (; i < n4; i += stride) {
        float4 e = ((const float4*)out)[i];
        int4  s4 = ((const int4*)idx)[i];
        float4 r;
        r.x = e.x / segsum[s4.x];
        r.y = e.y / segsum[s4.y];
        r.z = e.z / segsum[s4.z];
        r.w = e.w / segsum[s4.w];
        ((float4*)out)[i] = r;
    }
    if (blockIdx.x == 0 && threadIdx.x < (n & 3)) {
        int j = (n & ~3) + threadIdx.x;
        out[j] = out[j] / segsum[idx[j]];
    }
}

extern "C" void kernel_launch(void* const* d_in, const int* in_sizes, int n_in,
                              void* d_out, int out_size, void* d_ws, size_t ws_size,
                              hipStream_t stream)
{
    const float* x   = (const float*)d_in[0];
    const float* Wq  = (const float*)d_in[1];
    const float* bq  = (const float*)d_in[2];
    const float* Wk  = (const float*)d_in[3];
    const float* bk  = (const float*)d_in[4];
    const int*   idx = (const int*)d_in[5];
    const int n = in_sizes[5];

    float* segsum = (float*)d_ws;  // NSEG floats

    (void)hipMemsetAsync(segsum, 0, (size_t)NSEG * 4, stream);

    const int nsub = (n + 15) >> 4;           // 16-row subtiles
    int grid1 = 768;                          // 3 blocks/CU (32KB LDS, VGPR<=170)
    if (grid1 * 4 > nsub) grid1 = (nsub + 3) / 4;
    att_kernel<<<grid1, 256, 0, stream>>>(x, Wq, bq, Wk, bk, idx,
                                          (float*)d_out, segsum, n, nsub);

    int n4 = n >> 2;
    int grid2 = (n4 + 255) / 256;
    if (grid2 > 1024) grid2 = 1024;
    if (grid2 < 1) grid2 = 1;
    norm_kernel<<<grid2, 256, 0, stream>>>(idx, segsum, (float*)d_out, n);
}

// Round 13
// 199.243 us; speedup vs baseline: 1.1509x; 1.1509x over previous
//
#include <hip/hip_runtime.h>
#include <hip/hip_fp16.h>
#include <math.h>

#define IN_DIM 256
#define HID 32
#define NSEG 100000
#define ROWB 1024     // bytes per x-row (256 f32)
#define WBUF 16384    // one X buffer: 16 rows x 1KB

typedef _Float16 half8 __attribute__((ext_vector_type(8)));
typedef __fp16  fp16x2 __attribute__((ext_vector_type(2)));   // cvt_pkrtz return type
typedef float floatx4 __attribute__((ext_vector_type(4)));

// async global->LDS, 16B per lane, dest = wave-uniform base + lane*16 (m104).
// aux=2 = NT (legacy slc bit -> nt on gfx94x+): x is a zero-reuse 1GB stream;
// non-temporal policy keeps L2/IC residency for segsum (atomics) and idx.
__device__ __forceinline__ void gload_lds16_nt(const float* g, char* l) {
    __builtin_amdgcn_global_load_lds(
        (const __attribute__((address_space(1))) void*)g,
        (__attribute__((address_space(3))) void*)l,
        16, 0, 2 /* NT */);
}

// Fused q/k projection (f16 MFMA, fp32 accum) + per-row dot + exp + segment-sum.
// Structure = R11 (best, 218.6): per-wave LDS double-buffer, barrier-free,
// counted vmcnt drain (stage loads retired, idx/store/atomic ride across the
// iteration boundary). R13 delta: NT cache policy on the x stream + NT store
// for e_out, so the small hot structures (segsum, idx) stay cache-resident.
__global__ __launch_bounds__(128) void att_kernel(
    const float* __restrict__ x,
    const float* __restrict__ Wq, const float* __restrict__ bq,
    const float* __restrict__ Wk, const float* __restrict__ bk,
    const int* __restrict__ idx,
    float* __restrict__ e_out, float* __restrict__ segsum,
    int n, int nsub)
{
    extern __shared__ char smem[];   // 64KB: BF (32KB, prologue) overlapped with 2 waves x 2x16KB

    const int tid = threadIdx.x;
    const int w  = tid >> 6, l = tid & 63;   // w in {0,1}
    const int lr = l & 15,  lg = l >> 4;

    // ---- prologue (block-wide, barriers ok): pack B fragments, copy to VGPRs
    {
        _Float16* BF = (_Float16*)smem;
#pragma unroll
        for (int rr = 0; rr < 2; ++rr) {
            const int k = tid + rr * 128;             // W row (0..255)
            const int ks = k >> 5, lg2 = (k >> 3) & 3, j = k & 7;
            const float4* wqr = (const float4*)(Wq + (size_t)k * HID);
            const float4* wkr = (const float4*)(Wk + (size_t)k * HID);
#pragma unroll
            for (int i = 0; i < 8; ++i) {
                float4 vq = wqr[i];
                float4 vk = wkr[i];
                float fq[4] = { vq.x, vq.y, vq.z, vq.w };
                float fk[4] = { vk.x, vk.y, vk.z, vk.w };
#pragma unroll
                for (int u2 = 0; u2 < 4; ++u2) {
                    int c = i * 4 + u2, cg = c >> 4, cr = c & 15;
                    BF[(((cg    ) * 8 + ks) * 64 + lg2 * 16 + cr) * 8 + j] = (_Float16)fq[u2];
                    BF[(((cg + 2) * 8 + ks) * 64 + lg2 * 16 + cr) * 8 + j] = (_Float16)fk[u2];
                }
            }
        }
    }
    __syncthreads();
    half8 b[4][8];   // 128 VGPR: b[cg][ks], cg = {q0,q1,k0,k1}
    {
        const _Float16* bfl = (const _Float16*)smem + (size_t)l * 8;
#pragma unroll
        for (int cg = 0; cg < 4; ++cg)
#pragma unroll
            for (int ks = 0; ks < 8; ++ks)
                b[cg][ks] = *(const half8*)(bfl + (cg * 8 + ks) * 512);
    }
    __syncthreads();   // BF consumed; smem free for per-wave X buffers

    const float bq0 = bq[lr], bq1 = bq[lr + 16];
    const float bk0 = bk[lr], bk1 = bk[lr + 16];

    char* const Xw = smem + w * (2 * WBUF);   // this wave's two buffers
    const int sw = lr & 7;

    // stage subtile s into buffer: LDS linear, source pre-swizzled
    //   LDS[r][chunk c] = G[row][c ^ (r&7)]  (16B chunks), NT policy
    auto stage = [&](int s, int bufsel) {
        char* buf = Xw + bufsel * WBUF;
#pragma unroll
        for (int r = 0; r < 16; ++r) {
            int grow = s * 16 + r;
            if (grow >= n) grow = n - 1;
            const float* src = x + (size_t)grow * IN_DIM + ((l ^ (r & 7)) << 2);
            gload_lds16_nt(src, buf + r * ROWB);
        }
    };

    const int gw      = blockIdx.x * 2 + w;
    const int gstride = gridDim.x * 2;

    int s = gw;
    if (s >= nsub) return;   // after both barriers: safe

    int cur = 0;
    stage(s, 0);
    // idx for subtile s's epilogue (unconditional, clamped: deterministic FIFO count)
    int r_ep = s * 16 + lg * 4 + lr;
    int my_seg = idx[r_ep < n ? r_ep : (n - 1)];
    asm volatile("s_waitcnt vmcnt(0)" ::: "memory");   // prologue drain (once)
    __builtin_amdgcn_sched_barrier(0);

    while (true) {
        const int snext = s + gstride;

        // ---- issue next subtile's stream FIRST: 16 stage loads, then idx
        int r_next = 0, seg_next = 0;
        if (snext < nsub) {
            stage(snext, cur ^ 1);
            __builtin_amdgcn_sched_barrier(0);         // pin: stage BEFORE idx
            r_next = snext * 16 + lg * 4 + lr;
            seg_next = idx[r_next < n ? r_next : (n - 1)];
        }
        __builtin_amdgcn_sched_barrier(0);

        // ---- compute from buf[cur] (its loads were drained last iteration)
        const char* Xr = Xw + cur * WBUF + lr * ROWB;
        floatx4 acc0 = {0.f,0.f,0.f,0.f}, acc1 = {0.f,0.f,0.f,0.f};
        floatx4 acc2 = {0.f,0.f,0.f,0.f}, acc3 = {0.f,0.f,0.f,0.f};
#pragma unroll
        for (int ks = 0; ks < 8; ++ks) {
            float4 v0 = *(const float4*)(Xr + ks * 128 + (((lg * 2 + 0) ^ sw) << 4));
            float4 v1 = *(const float4*)(Xr + ks * 128 + (((lg * 2 + 1) ^ sw) << 4));
            union { half8 h8; fp16x2 h2[4]; } u;
            u.h2[0] = __builtin_amdgcn_cvt_pkrtz(v0.x, v0.y);
            u.h2[1] = __builtin_amdgcn_cvt_pkrtz(v0.z, v0.w);
            u.h2[2] = __builtin_amdgcn_cvt_pkrtz(v1.x, v1.y);
            u.h2[3] = __builtin_amdgcn_cvt_pkrtz(v1.z, v1.w);
            acc0 = __builtin_amdgcn_mfma_f32_16x16x32_f16(u.h8, b[0][ks], acc0, 0, 0, 0);
            acc1 = __builtin_amdgcn_mfma_f32_16x16x32_f16(u.h8, b[1][ks], acc1, 0, 0, 0);
            acc2 = __builtin_amdgcn_mfma_f32_16x16x32_f16(u.h8, b[2][ks], acc2, 0, 0, 0);
            acc3 = __builtin_amdgcn_mfma_f32_16x16x32_f16(u.h8, b[3][ks], acc3, 0, 0, 0);
        }

        // att = sum_h (qv+bq)*(kv+bk); reduce over the 16 col-lanes
        float p[4];
#pragma unroll
        for (int i2 = 0; i2 < 4; ++i2) {
            p[i2] = (acc0[i2] + bq0) * (acc2[i2] + bk0)
                  + (acc1[i2] + bq1) * (acc3[i2] + bk1);
            p[i2] += __shfl_xor(p[i2], 1);
            p[i2] += __shfl_xor(p[i2], 2);
            p[i2] += __shfl_xor(p[i2], 4);
            p[i2] += __shfl_xor(p[i2], 8);
        }

        // epilogue: store (NT) + atomic fire-and-forget (ride across the
        // iteration boundary — the counted drain below never waits for them)
        if (lr < 4 && r_ep < n) {
            float pv = (lr & 1) ? ((lr & 2) ? p[3] : p[1])
                                : ((lr & 2) ? p[2] : p[0]);
            float e = __expf(pv);   // no max-subtract: |att| small enough for f32
            __builtin_nontemporal_store(e, &e_out[r_ep]);
            atomicAdd(&segsum[my_seg], e);
        }

        if (snext >= nsub) break;

        // own ds_reads retired -> buf[cur] safe to restage next iteration
        asm volatile("s_waitcnt lgkmcnt(0)" ::: "memory");
        // COUNTED drain: outstanding FIFO = [stage(snext) x16, idx, store, atomic];
        // vmcnt(3) retires exactly the 16 stage loads (in-order retirement, m135)
        asm volatile("s_waitcnt vmcnt(3)" ::: "memory");
        __builtin_amdgcn_sched_barrier(0);

        s = snext;
        r_ep = r_next;
        my_seg = seg_next;
        cur ^= 1;
    }
}

// out = e / segsum[idx], float4-vectorized
__global__ __launch_bounds__(256) void norm_kernel(
    const int* __restrict__ idx, const float* __restrict__ segsum,
    float* __restrict__ out, int n)
{
    int i = blockIdx.x * blockDim.x + threadIdx.x;
    int stride = gridDim.x * blockDim.x;
    int n4 = n >> 2;
    for (; i < n4; i += stride) {
        float4 e = ((const float4*)out)[i];
        int4  s4 = ((const int4*)idx)[i];
        float4 r;
        r.x = e.x / segsum[s4.x];
        r.y = e.y / segsum[s4.y];
        r.z = e.z / segsum[s4.z];
        r.w = e.w / segsum[s4.w];
        ((float4*)out)[i] = r;
    }
    if (blockIdx.x == 0 && threadIdx.x < (n & 3)) {
        int j = (n & ~3) + threadIdx.x;
        out[j] = out[j] / segsum[idx[j]];
    }
}

extern "C" void kernel_launch(void* const* d_in, const int* in_sizes, int n_in,
                              void* d_out, int out_size, void* d_ws, size_t ws_size,
                              hipStream_t stream)
{
    const float* x   = (const float*)d_in[0];
    const float* Wq  = (const float*)d_in[1];
    const float* bq  = (const float*)d_in[2];
    const float* Wk  = (const float*)d_in[3];
    const float* bk  = (const float*)d_in[4];
    const int*   idx = (const int*)d_in[5];
    const int n = in_sizes[5];

    float* segsum = (float*)d_ws;  // NSEG floats

    (void)hipMemsetAsync(segsum, 0, (size_t)NSEG * 4, stream);

    const int nsub = (n + 15) >> 4;           // 16-row subtiles
    int grid1 = 512;                          // 2 blocks/CU (64KB LDS), 1024 wave-streams
    if (grid1 * 2 > nsub) grid1 = (nsub + 1) / 2;
    att_kernel<<<grid1, 128, 65536, stream>>>(x, Wq, bq, Wk, bk, idx,
                                              (float*)d_out, segsum, n, nsub);

    int n4 = n >> 2;
    int grid2 = (n4 + 255) / 256;
    if (grid2 > 1024) grid2 = 1024;
    if (grid2 < 1) grid2 = 1;
    norm_kernel<<<grid2, 256, 0, stream>>>(idx, segsum, (float*)d_out, n);
}

// Round 15
// 198.109 us; speedup vs baseline: 1.1575x; 1.0057x over previous
//
#include <hip/hip_runtime.h>
#include <hip/hip_fp16.h>
#include <math.h>

#define IN_DIM 256
#define HID 32
#define NSEG 100000
#define ROWB 1024     // bytes per x-row (256 f32)
#define WBUF 16384    // one X buffer: 16 rows x 1KB

typedef _Float16 half8 __attribute__((ext_vector_type(8)));
typedef __fp16  fp16x2 __attribute__((ext_vector_type(2)));   // cvt_pkrtz return type
typedef float floatx4 __attribute__((ext_vector_type(4)));
typedef int   intx4   __attribute__((ext_vector_type(4)));

// async global->LDS, 16B per lane, dest = wave-uniform base + lane*16 (m104).
// aux=2 = NT: x is a zero-reuse 1GB stream; keeps L2/IC residency for segsum/idx.
__device__ __forceinline__ void gload_lds16_nt(const float* g, char* l) {
    __builtin_amdgcn_global_load_lds(
        (const __attribute__((address_space(1))) void*)g,
        (__attribute__((address_space(3))) void*)l,
        16, 0, 2 /* NT */);
}

// Fused q/k projection (f16 MFMA, fp32 accum) + per-row dot + exp + segment-sum.
// R15 = R14 with the nontemporal builtins applied to ext_vector types (compile
// fix). Structure: NT x-stream + per-wave LDS dbuf + counted drains + DEPTH-2
// pipeline: after compute(s) finishes reading buf[cur] (lgkmcnt 0), buf[cur]
// is restaged with s+2g BEFORE the drain; the drain waits only for stage(s+g)
// (vmcnt counted, in-order FIFO retirement) while stage(s+2g) flies on.
__global__ __launch_bounds__(128) void att_kernel(
    const float* __restrict__ x,
    const float* __restrict__ Wq, const float* __restrict__ bq,
    const float* __restrict__ Wk, const float* __restrict__ bk,
    const int* __restrict__ idx,
    float* __restrict__ e_out, float* __restrict__ segsum,
    int n, int nsub)
{
    extern __shared__ char smem[];   // 64KB: BF (32KB, prologue) overlapped with 2 waves x 2x16KB

    const int tid = threadIdx.x;
    const int w  = tid >> 6, l = tid & 63;   // w in {0,1}
    const int lr = l & 15,  lg = l >> 4;

    // ---- prologue (block-wide, barriers ok): pack B fragments, copy to VGPRs
    {
        _Float16* BF = (_Float16*)smem;
#pragma unroll
        for (int rr = 0; rr < 2; ++rr) {
            const int k = tid + rr * 128;             // W row (0..255)
            const int ks = k >> 5, lg2 = (k >> 3) & 3, j = k & 7;
            const float4* wqr = (const float4*)(Wq + (size_t)k * HID);
            const float4* wkr = (const float4*)(Wk + (size_t)k * HID);
#pragma unroll
            for (int i = 0; i < 8; ++i) {
                float4 vq = wqr[i];
                float4 vk = wkr[i];
                float fq[4] = { vq.x, vq.y, vq.z, vq.w };
                float fk[4] = { vk.x, vk.y, vk.z, vk.w };
#pragma unroll
                for (int u2 = 0; u2 < 4; ++u2) {
                    int c = i * 4 + u2, cg = c >> 4, cr = c & 15;
                    BF[(((cg    ) * 8 + ks) * 64 + lg2 * 16 + cr) * 8 + j] = (_Float16)fq[u2];
                    BF[(((cg + 2) * 8 + ks) * 64 + lg2 * 16 + cr) * 8 + j] = (_Float16)fk[u2];
                }
            }
        }
    }
    __syncthreads();
    half8 b[4][8];   // 128 VGPR: b[cg][ks], cg = {q0,q1,k0,k1}
    {
        const _Float16* bfl = (const _Float16*)smem + (size_t)l * 8;
#pragma unroll
        for (int cg = 0; cg < 4; ++cg)
#pragma unroll
            for (int ks = 0; ks < 8; ++ks)
                b[cg][ks] = *(const half8*)(bfl + (cg * 8 + ks) * 512);
    }
    __syncthreads();   // BF consumed; smem free for per-wave X buffers

    const float bq0 = bq[lr], bq1 = bq[lr + 16];
    const float bk0 = bk[lr], bk1 = bk[lr + 16];

    char* const Xw = smem + w * (2 * WBUF);   // this wave's two buffers
    const int sw = lr & 7;

    // stage subtile s into buffer: LDS linear, source pre-swizzled, NT policy
    //   LDS[r][chunk c] = G[row][c ^ (r&7)]  (16B chunks)
    auto stage = [&](int s, int bufsel) {
        char* buf = Xw + bufsel * WBUF;
#pragma unroll
        for (int r = 0; r < 16; ++r) {
            int grow = s * 16 + r;
            if (grow >= n) grow = n - 1;
            const float* src = x + (size_t)grow * IN_DIM + ((l ^ (r & 7)) << 2);
            gload_lds16_nt(src, buf + r * ROWB);
        }
    };

    const int gw = blockIdx.x * 2 + w;
    const int g  = gridDim.x * 2;

    int s = gw;
    if (s >= nsub) return;   // after both barriers: safe

    // ---- prologue pipeline fill: stage(s)->buf0 [, stage(s+g)->buf1]
    stage(s, 0);
    int r0 = s * 16 + lg * 4 + lr;
    int seg0 = idx[r0 < n ? r0 : (n - 1)];
    const bool have1 = (s + g < nsub);
    int r1 = 0, seg1 = 0;
    if (have1) {
        stage(s + g, 1);
        r1 = (s + g) * 16 + lg * 4 + lr;
        seg1 = idx[r1 < n ? r1 : (n - 1)];
    }
    // drain stage(s): guaranteed-newer ops = idx(s) [+ stage(s+g)+idx = 17]
    if (have1) { asm volatile("s_waitcnt vmcnt(18)" ::: "memory"); }
    else       { asm volatile("s_waitcnt vmcnt(1)"  ::: "memory"); }
    __builtin_amdgcn_sched_barrier(0);

    int cur = 0;
    while (true) {
        // ---- compute s from buf[cur] (its DMA completion was drained earlier)
        const char* Xr = Xw + cur * WBUF + lr * ROWB;
        floatx4 acc0 = {0.f,0.f,0.f,0.f}, acc1 = {0.f,0.f,0.f,0.f};
        floatx4 acc2 = {0.f,0.f,0.f,0.f}, acc3 = {0.f,0.f,0.f,0.f};
#pragma unroll
        for (int ks = 0; ks < 8; ++ks) {
            float4 v0 = *(const float4*)(Xr + ks * 128 + (((lg * 2 + 0) ^ sw) << 4));
            float4 v1 = *(const float4*)(Xr + ks * 128 + (((lg * 2 + 1) ^ sw) << 4));
            union { half8 h8; fp16x2 h2[4]; } u;
            u.h2[0] = __builtin_amdgcn_cvt_pkrtz(v0.x, v0.y);
            u.h2[1] = __builtin_amdgcn_cvt_pkrtz(v0.z, v0.w);
            u.h2[2] = __builtin_amdgcn_cvt_pkrtz(v1.x, v1.y);
            u.h2[3] = __builtin_amdgcn_cvt_pkrtz(v1.z, v1.w);
            acc0 = __builtin_amdgcn_mfma_f32_16x16x32_f16(u.h8, b[0][ks], acc0, 0, 0, 0);
            acc1 = __builtin_amdgcn_mfma_f32_16x16x32_f16(u.h8, b[1][ks], acc1, 0, 0, 0);
            acc2 = __builtin_amdgcn_mfma_f32_16x16x32_f16(u.h8, b[2][ks], acc2, 0, 0, 0);
            acc3 = __builtin_amdgcn_mfma_f32_16x16x32_f16(u.h8, b[3][ks], acc3, 0, 0, 0);
        }

        // att = sum_h (qv+bq)*(kv+bk); reduce over the 16 col-lanes
        float p[4];
#pragma unroll
        for (int i2 = 0; i2 < 4; ++i2) {
            p[i2] = (acc0[i2] + bq0) * (acc2[i2] + bk0)
                  + (acc1[i2] + bq1) * (acc3[i2] + bk1);
            p[i2] += __shfl_xor(p[i2], 1);
            p[i2] += __shfl_xor(p[i2], 2);
            p[i2] += __shfl_xor(p[i2], 4);
            p[i2] += __shfl_xor(p[i2], 8);
        }

        // all own ds_reads (incl. shfl) retired -> buf[cur] safe to restage
        asm volatile("s_waitcnt lgkmcnt(0)" ::: "memory");
        __builtin_amdgcn_sched_barrier(0);

        // ---- depth-2 refill: stage(s+2g) into buf[cur], BEFORE the drain
        const int s2 = s + 2 * g;
        const bool refill = (s2 < nsub);
        int r2 = 0, seg2 = 0;
        if (refill) {
            stage(s2, cur);
            __builtin_amdgcn_sched_barrier(0);   // pin: stage BEFORE idx
            r2 = s2 * 16 + lg * 4 + lr;
            seg2 = idx[r2 < n ? r2 : (n - 1)];
        }
        __builtin_amdgcn_sched_barrier(0);

        // ---- epilogue(s): NT store + atomic, fire-and-forget
        if (lr < 4 && r0 < n) {
            float pv = (lr & 1) ? ((lr & 2) ? p[3] : p[1])
                                : ((lr & 2) ? p[2] : p[0]);
            float e = __expf(pv);   // no max-subtract: |att| small enough for f32
            __builtin_nontemporal_store(e, &e_out[r0]);
            atomicAdd(&segsum[seg0], e);
        }

        if (s + g >= nsub) break;

        // ---- counted drain: ensure stage(s+g) retired (in-order FIFO).
        // Guaranteed-issued newer ops: idx(s+g)=1, [stage(s2)+idx=17], store+atomic(s)=2
        if (refill) { asm volatile("s_waitcnt vmcnt(20)" ::: "memory"); }
        else        { asm volatile("s_waitcnt vmcnt(3)"  ::: "memory"); }
        __builtin_amdgcn_sched_barrier(0);

        s += g;
        cur ^= 1;
        r0 = r1; seg0 = seg1;
        r1 = r2; seg1 = seg2;
    }
}

// out = e / segsum[idx], vectorized, NT on the streams (ext_vector types)
__global__ __launch_bounds__(256) void norm_kernel(
    const int* __restrict__ idx, const float* __restrict__ segsum,
    float* __restrict__ out, int n)
{
    int i = blockIdx.x * blockDim.x + threadIdx.x;
    int stride = gridDim.x * blockDim.x;
    int n4 = n >> 2;
    for (; i < n4; i += stride) {
        floatx4 e = __builtin_nontemporal_load((const floatx4*)out + i);
        intx4  s4 = __builtin_nontemporal_load((const intx4*)idx + i);
        floatx4 r;
        r[0] = e[0] / segsum[s4[0]];
        r[1] = e[1] / segsum[s4[1]];
        r[2] = e[2] / segsum[s4[2]];
        r[3] = e[3] / segsum[s4[3]];
        __builtin_nontemporal_store(r, (floatx4*)out + i);
    }
    if (blockIdx.x == 0 && threadIdx.x < (n & 3)) {
        int j = (n & ~3) + threadIdx.x;
        out[j] = out[j] / segsum[idx[j]];
    }
}

extern "C" void kernel_launch(void* const* d_in, const int* in_sizes, int n_in,
                              void* d_out, int out_size, void* d_ws, size_t ws_size,
                              hipStream_t stream)
{
    const float* x   = (const float*)d_in[0];
    const float* Wq  = (const float*)d_in[1];
    const float* bq  = (const float*)d_in[2];
    const float* Wk  = (const float*)d_in[3];
    const float* bk  = (const float*)d_in[4];
    const int*   idx = (const int*)d_in[5];
    const int n = in_sizes[5];

    float* segsum = (float*)d_ws;  // NSEG floats

    (void)hipMemsetAsync(segsum, 0, (size_t)NSEG * 4, stream);

    const int nsub = (n + 15) >> 4;           // 16-row subtiles
    int grid1 = 512;                          // 2 blocks/CU (64KB LDS), 1024 wave-streams
    if (grid1 * 2 > nsub) grid1 = (nsub + 1) / 2;
    att_kernel<<<grid1, 128, 65536, stream>>>(x, Wq, bq, Wk, bk, idx,
                                              (float*)d_out, segsum, n, nsub);

    int n4 = n >> 2;
    int grid2 = (n4 + 255) / 256;
    if (grid2 > 1024) grid2 = 1024;
    if (grid2 < 1) grid2 = 1;
    norm_kernel<<<grid2, 256, 0, stream>>>(idx, segsum, (float*)d_out, n);
}